// Round 20
// baseline (2449.413 us; speedup 1.0000x reference)
//
#include <hip/hip_runtime.h>
#include <math.h>

#define B_    64
#define S_    1024
#define DK_   128
#define DV_   128
#define T_    16
#define NC_   (S_ / T_)
#define KP_   132          // padded LDS row stride
#define LR_   0.1f
#define LRP1_ 1.1f
#define THR_  0.1f
#define ITEMP_ 10.0f
#define EPS_  1e-6f

template<int CTRL>
__device__ __forceinline__ float dpp_add(float x) {
  int t = __builtin_amdgcn_update_dpp(0, __float_as_int(x), CTRL, 0xf, 0xf, true);
  return x + __int_as_float(t);
}
__device__ __forceinline__ float wave_sum64(float x) {
  x = dpp_add<0x111>(x); x = dpp_add<0x112>(x); x = dpp_add<0x114>(x);
  x = dpp_add<0x118>(x); x = dpp_add<0x142>(x); x = dpp_add<0x143>(x);
  return __int_as_float(__builtin_amdgcn_readlane(__float_as_int(x), 63));
}
__device__ __forceinline__ float row16_sum(float x) {  // valid in lane 15 of each 16-group
  x = dpp_add<0x111>(x); x = dpp_add<0x112>(x);
  x = dpp_add<0x114>(x); x = dpp_add<0x118>(x);
  return x;
}
__device__ __forceinline__ float rdlane(float v, int l) {
  return __int_as_float(__builtin_amdgcn_readlane(__float_as_int(v), l));
}
__device__ __forceinline__ float dot4(float4 a, float4 b) {
  return fmaf(a.x, b.x, fmaf(a.y, b.y, fmaf(a.z, b.z, a.w * b.w)));
}
__device__ __forceinline__ void gll16(const float* g, float* l) {
  __builtin_amdgcn_global_load_lds(
      (const __attribute__((address_space(1))) unsigned int*)g,
      (__attribute__((address_space(3))) unsigned int*)l, 16, 0, 0);
}
#define PIN4(v) asm volatile("" : "+v"(v.x), "+v"(v.y), "+v"(v.z), "+v"(v.w))

__global__ __launch_bounds__(512, 2)
void sgm_kernel(const float* __restrict__ mem_in,
                const float* __restrict__ key,
                const float* __restrict__ value,
                float* __restrict__ out) {
  const int b = blockIdx.x, tid = threadIdx.x;
  const int g = tid >> 4, h = tid & 15, lane = tid & 63, wv = tid >> 6;

  __shared__ __align__(16) float kS[2][T_][KP_];   // k copy: read ONLY by Gram
  __shared__ __align__(16) float vS[2][T_][KP_];   // v: read ONLY by serial (wave0)
  __shared__ __align__(16) float rawL[T_][KP_];
  __shared__ __align__(16) float cuL[T_][DK_];
  __shared__ __align__(16) float GT[2][T_][T_];    // GT[p][t][j] = k_j.k_t (j<=t)
  __shared__ __align__(16) float gateL[S_];

  float4 mA[4], mB[4];
  {
    const float4* Mp = reinterpret_cast<const float4*>(mem_in + (size_t)b * DV_ * DK_);
    #pragma unroll
    for (int rr = 0; rr < 4; ++rr) {
      mA[rr] = Mp[(4*g + rr) * 32 + h];
      mB[rr] = Mp[(4*g + rr) * 32 + 16 + h];
    }
  }
  const float* kb = key   + (size_t)b * S_ * DK_;
  const float* vb = value + (size_t)b * S_ * DV_;

  float4 kxR[T_], kyR[T_];   // current chunk's k, cols 4h.. and 64+4h..

  auto stage = [&](int cc) {
    if (wv == 1 && lane < 32) {
      #pragma unroll
      for (int t = 0; t < T_; ++t)
        gll16(kb + (size_t)(cc*T_ + t)*DK_ + lane*4, &kS[cc & 1][t][0]);
    }
    if (wv == 2 && lane < 32) {
      #pragma unroll
      for (int t = 0; t < T_; ++t)
        gll16(vb + (size_t)(cc*T_ + t)*DV_ + lane*4, &vS[cc & 1][t][0]);
    }
  };

  auto loadK = [&](int cc) {   // direct global -> regs (L2/L3-hot), pinned
    const float4* kg = reinterpret_cast<const float4*>(kb + (size_t)cc * T_ * DK_);
    #pragma unroll
    for (int t = 0; t < T_; ++t) {
      kxR[t] = kg[t*32 + h];
      kyR[t] = kg[t*32 + 16 + h];
      PIN4(kxR[t]); PIN4(kyR[t]);
    }
  };

  auto gramPhase = [&](int cc) {   // waves 1-7: 136 pairs (incl diag) x 2-lane teams
    const int cb1 = cc & 1;
    const int p = (tid - 64) >> 1, h2 = tid & 1;
    if (wv > 0 && p < 136) {
      int t = 0, pp = p;
      while (pp > t) { pp -= (t + 1); ++t; }   // p = t(t+1)/2 + j, j<=t
      const int j = pp;
      const float4* kj4 = reinterpret_cast<const float4*>(&kS[cb1][j][h2*64]);
      const float4* kt4 = reinterpret_cast<const float4*>(&kS[cb1][t][h2*64]);
      float acc = 0.f;
      #pragma unroll
      for (int i = 0; i < 16; ++i) acc += dot4(kj4[i], kt4[i]);
      int sw = __builtin_amdgcn_update_dpp(0, __float_as_int(acc), 0xB1, 0xf, 0xf, true);
      const float tot = acc + __int_as_float(sw);
      if (h2 == 0) GT[cb1][t][j] = tot;
    }
  };

  // ---- prologue: chunks 0,1 staged; Gram(0) ready ----
  loadK(0);
  stage(0); stage(1);
  __syncthreads();                       // drains vmcnt for all (incl. stager waves)
  gramPhase(0);
  asm volatile("s_waitcnt lgkmcnt(0)" ::: "memory");
  __builtin_amdgcn_s_barrier();
  asm volatile("" ::: "memory");

  for (int c = 0; c < NC_; ++c) {
    const int cb = c & 1;

    // ---- matvec raw_t = M . k_t  (k from regs, zero LDS) ----
    #pragma unroll
    for (int t = 0; t < T_; ++t) {
      float a0 = dot4(mA[0], kxR[t]) + dot4(mB[0], kyR[t]);
      float a1 = dot4(mA[1], kxR[t]) + dot4(mB[1], kyR[t]);
      float a2 = dot4(mA[2], kxR[t]) + dot4(mB[2], kyR[t]);
      float a3 = dot4(mA[3], kxR[t]) + dot4(mB[3], kyR[t]);
      a0 = row16_sum(a0); a1 = row16_sum(a1);
      a2 = row16_sum(a2); a3 = row16_sum(a3);
      if (h == 15)
        *reinterpret_cast<float4*>(&rawL[t][4*g]) = make_float4(a0, a1, a2, a3);
    }

    // stager waves: chunk c+1's DMA (issued at bottom of iter c-1) must be in LDS
    if (wv == 1 || wv == 2) asm volatile("s_waitcnt vmcnt(0)" ::: "memory");
    asm volatile("s_waitcnt lgkmcnt(0)" ::: "memory");
    __builtin_amdgcn_s_barrier();        // bar2: rawL + kS/vS(c+1) ready
    asm volatile("" ::: "memory");

    if (wv == 0) {
      // ---- serial phase (overlapped with waves 1-7's Gram below) ----
      const int sj = lane & 15;
      const float rinv = 1.0f / (sqrtf(GT[cb][sj][sj]) + EPS_);
      float cu0[T_], cu1[T_];
      #pragma unroll
      for (int t = 0; t < T_; ++t) {
        const float grt = GT[cb][t][sj];        // lane sj holds G[j=sj][t]
        const float rin_t = rdlane(rinv, t);
        float y0 = 0.f, y1 = 0.f;
        #pragma unroll
        for (int j = 0; j < T_; ++j) if (j < t) {
          const float gjt = rdlane(grt, j);
          y0 = fmaf(gjt, cu0[j], y0);
          y1 = fmaf(gjt, cu1[j], y1);
        }
        const float2 rv  = *reinterpret_cast<const float2*>(&rawL[t][2*lane]);
        const float2 vvt = *reinterpret_cast<const float2*>(&vS[cb][t][2*lane]);
        const float pred0 = rin_t * (rv.x - y0);
        const float pred1 = rin_t * (rv.y - y1);
        const float s0 = pred0 - vvt.x, s1 = pred1 - vvt.y;
        const float s2 = wave_sum64(fmaf(s0, s0, s1 * s1));
        const float gg = 1.0f / (1.0f + __expf((THR_ - sqrtf(s2)) * ITEMP_));
        if (lane == 0) gateL[c*T_ + t] = gg;
        const float ct = gg * rin_t;
        const float u0 = fmaf(LRP1_, pred0, -(LR_ * vvt.x));
        const float u1 = fmaf(LRP1_, pred1, -(LR_ * vvt.y));
        cu0[t] = ct * u0; cu1[t] = ct * u1;
        *reinterpret_cast<float2*>(&cuL[t][2*lane]) = make_float2(cu0[t], cu1[t]);
      }
    } else {
      if (c + 1 < NC_) gramPhase(c + 1);  // next chunk's Gram under serial(c)
    }

    asm volatile("s_waitcnt lgkmcnt(0)" ::: "memory");
    __builtin_amdgcn_s_barrier();        // bar3: cuL + GT(c+1) visible; vS(c) reads done
    asm volatile("" ::: "memory");

    // ---- update M -= sum_j cu_j (x) k_j  (k from regs) ----
    #pragma unroll
    for (int j = 0; j < T_; ++j) {
      const float4 cu = *reinterpret_cast<const float4*>(&cuL[j][4*g]);
      const float cc4[4] = {cu.x, cu.y, cu.z, cu.w};
      #pragma unroll
      for (int rr = 0; rr < 4; ++rr) {
        mA[rr].x = fmaf(-cc4[rr], kxR[j].x, mA[rr].x);
        mA[rr].y = fmaf(-cc4[rr], kxR[j].y, mA[rr].y);
        mA[rr].z = fmaf(-cc4[rr], kxR[j].z, mA[rr].z);
        mA[rr].w = fmaf(-cc4[rr], kxR[j].w, mA[rr].w);
        mB[rr].x = fmaf(-cc4[rr], kyR[j].x, mB[rr].x);
        mB[rr].y = fmaf(-cc4[rr], kyR[j].y, mB[rr].y);
        mB[rr].z = fmaf(-cc4[rr], kyR[j].z, mB[rr].z);
        mB[rr].w = fmaf(-cc4[rr], kyR[j].w, mB[rr].w);
      }
    }

    if (c + 1 < NC_) loadK(c + 1);       // refill k regs (after update consumed them)
    if (c + 2 < NC_) stage(c + 2);       // SAFE here: parity-cb readers retired at bar3
  }

  // ---- outputs ----
  {
    float4* Op = reinterpret_cast<float4*>(out + (size_t)b * DV_ * DK_);
    #pragma unroll
    for (int rr = 0; rr < 4; ++rr) {
      Op[(4*g + rr) * 32 + h] = mA[rr];
      Op[(4*g + rr) * 32 + 16 + h] = mB[rr];
    }
    float2* Gp = reinterpret_cast<float2*>(out + (size_t)B_ * DV_ * DK_ + (size_t)b * S_);
    Gp[tid] = reinterpret_cast<const float2*>(gateL)[tid];
  }
}

extern "C" void kernel_launch(void* const* d_in, const int* in_sizes, int n_in,
                              void* d_out, int out_size, void* d_ws, size_t ws_size,
                              hipStream_t stream) {
  const float* mem = (const float*)d_in[0];
  const float* key = (const float*)d_in[1];
  const float* val = (const float*)d_in[2];
  float* out = (float*)d_out;
  sgm_kernel<<<B_, 512, 0, stream>>>(mem, key, val, out);
}

// Round 21
// 1531.054 us; speedup vs baseline: 1.5998x; 1.5998x over previous
//
#include <hip/hip_runtime.h>
#include <math.h>

#define B_    64
#define S_    1024
#define DK_   128
#define DV_   128
#define T_    16
#define NC_   (S_ / T_)
#define KP_   132          // padded LDS row stride
#define LR_   0.1f
#define LRP1_ 1.1f
#define THR_  0.1f
#define ITEMP_ 10.0f
#define EPS_  1e-6f

template<int CTRL>
__device__ __forceinline__ float dpp_add(float x) {
  int t = __builtin_amdgcn_update_dpp(0, __float_as_int(x), CTRL, 0xf, 0xf, true);
  return x + __int_as_float(t);
}
__device__ __forceinline__ float wave_sum64(float x) {
  x = dpp_add<0x111>(x); x = dpp_add<0x112>(x); x = dpp_add<0x114>(x);
  x = dpp_add<0x118>(x); x = dpp_add<0x142>(x); x = dpp_add<0x143>(x);
  return __int_as_float(__builtin_amdgcn_readlane(__float_as_int(x), 63));
}
// sum over 32 consecutive lanes (a half-wave); valid in lanes 15,31 (47,63)
__device__ __forceinline__ float half32_sum(float x) {
  x = dpp_add<0x111>(x); x = dpp_add<0x112>(x);
  x = dpp_add<0x114>(x); x = dpp_add<0x118>(x);
  int t = __builtin_amdgcn_ds_swizzle(__float_as_int(x), 0x401F); // lane ^ 16
  return x + __int_as_float(t);
}
__device__ __forceinline__ float rdlane(float v, int l) {
  return __int_as_float(__builtin_amdgcn_readlane(__float_as_int(v), l));
}
__device__ __forceinline__ float dot4(float4 a, float4 b) {
  return fmaf(a.x, b.x, fmaf(a.y, b.y, fmaf(a.z, b.z, a.w * b.w)));
}
__device__ __forceinline__ void gll16(const float* g, float* l) {
  __builtin_amdgcn_global_load_lds(
      (const __attribute__((address_space(1))) unsigned int*)g,
      (__attribute__((address_space(3))) unsigned int*)l, 16, 0, 0);
}
#define PIN4(v) asm volatile("" : "+v"(v.x), "+v"(v.y), "+v"(v.z), "+v"(v.w))

__global__ __launch_bounds__(512, 2)
void sgm_kernel(const float* __restrict__ mem_in,
                const float* __restrict__ key,
                const float* __restrict__ value,
                float* __restrict__ out) {
  const int b = blockIdx.x, tid = threadIdx.x;
  const int g = tid >> 5;      // rowgroup 0..15 -> rows 8g..8g+7
  const int h = tid & 31;      // col chunk: float4 idx h within a row
  const int lane = tid & 63, wv = tid >> 6;

  __shared__ __align__(16) float kS[2][T_][KP_];   // k copy: Gram + kR refill only
  __shared__ __align__(16) float vS[2][T_][KP_];   // v: serial (wave0) only
  __shared__ __align__(16) float rawL[T_][KP_];
  __shared__ __align__(16) float cuL[T_][DK_];
  __shared__ __align__(16) float GT[2][T_][T_];    // GT[p][t][j] = k_j.k_t (j<=t)
  __shared__ __align__(16) float gateL[S_];

  float4 mR[8];   // rows 8g..8g+7, cols 4h..4h+3
  {
    const float4* Mp = reinterpret_cast<const float4*>(mem_in + (size_t)b * DV_ * DK_);
    #pragma unroll
    for (int rr = 0; rr < 8; ++rr) mR[rr] = Mp[(8*g + rr) * 32 + h];
  }
  const float* kb = key   + (size_t)b * S_ * DK_;
  const float* vb = value + (size_t)b * S_ * DV_;

  float4 kR[T_];  // whole chunk's k for this thread's 4 cols (64 VGPR, pinned)

  auto stage = [&](int cc) {
    if (wv == 1 && lane < 32) {
      #pragma unroll
      for (int t = 0; t < T_; ++t)
        gll16(kb + (size_t)(cc*T_ + t)*DK_ + lane*4, &kS[cc & 1][t][0]);
    }
    if (wv == 2 && lane < 32) {
      #pragma unroll
      for (int t = 0; t < T_; ++t)
        gll16(vb + (size_t)(cc*T_ + t)*DV_ + lane*4, &vS[cc & 1][t][0]);
    }
  };
  auto refillK = [&](int cc) {   // LDS -> regs, pinned (R18-proven scale)
    const int pb = cc & 1;
    #pragma unroll
    for (int t = 0; t < T_; ++t) {
      kR[t] = reinterpret_cast<const float4*>(&kS[pb][t][0])[h];
      PIN4(kR[t]);
    }
  };
  auto gramPhase = [&](int cc) {   // waves 1-7: 136 pairs (incl diag), 2-lane teams
    const int cb1 = cc & 1;
    const int p = (tid - 64) >> 1, h2 = tid & 1;
    if (wv > 0 && p < 136) {
      int t = 0, pp = p;
      while (pp > t) { pp -= (t + 1); ++t; }   // p = t(t+1)/2 + j, j<=t
      const int j = pp;
      const float4* kj4 = reinterpret_cast<const float4*>(&kS[cb1][j][h2*64]);
      const float4* kt4 = reinterpret_cast<const float4*>(&kS[cb1][t][h2*64]);
      float acc = 0.f;
      #pragma unroll
      for (int i = 0; i < 16; ++i) acc += dot4(kj4[i], kt4[i]);
      int sw = __builtin_amdgcn_update_dpp(0, __float_as_int(acc), 0xB1, 0xf, 0xf, true);
      const float tot = acc + __int_as_float(sw);
      if (h2 == 0) GT[cb1][t][j] = tot;
    }
  };

  // ---- prologue ----
  stage(0); stage(1);
  __syncthreads();               // drains vmcnt: kS/vS[0],[1] resident
  refillK(0);
  gramPhase(0);
  asm volatile("s_waitcnt lgkmcnt(0)" ::: "memory");
  __builtin_amdgcn_s_barrier();  // GT[0] visible
  asm volatile("" ::: "memory");

  for (int c = 0; c < NC_; ++c) {
    const int cb = c & 1;

    // ---- matvec raw_t = M . k_t  (zero LDS for k) ----
    #pragma unroll
    for (int t = 0; t < T_; ++t) {
      float a0 = dot4(mR[0], kR[t]), a1 = dot4(mR[1], kR[t]);
      float a2 = dot4(mR[2], kR[t]), a3 = dot4(mR[3], kR[t]);
      float a4 = dot4(mR[4], kR[t]), a5 = dot4(mR[5], kR[t]);
      float a6 = dot4(mR[6], kR[t]), a7 = dot4(mR[7], kR[t]);
      a0 = half32_sum(a0); a1 = half32_sum(a1); a2 = half32_sum(a2); a3 = half32_sum(a3);
      a4 = half32_sum(a4); a5 = half32_sum(a5); a6 = half32_sum(a6); a7 = half32_sum(a7);
      if (h == 31) {   // lanes 31,63: full 32-lane sums for rows 8g..8g+7
        *reinterpret_cast<float4*>(&rawL[t][8*g])     = make_float4(a0, a1, a2, a3);
        *reinterpret_cast<float4*>(&rawL[t][8*g + 4]) = make_float4(a4, a5, a6, a7);
      }
    }

    if (wv == 1 || wv == 2) asm volatile("s_waitcnt vmcnt(0)" ::: "memory");
    asm volatile("s_waitcnt lgkmcnt(0)" ::: "memory");
    __builtin_amdgcn_s_barrier();   // bar A: rawL ready; kS/vS[c+1] resident
    asm volatile("" ::: "memory");

    if (wv == 0) {
      // ---- serial phase (hidden under waves 1-7's Gram) ----
      const int sj = lane & 15;
      const float rinv = 1.0f / (sqrtf(GT[cb][sj][sj]) + EPS_);
      float cu0[T_], cu1[T_];
      #pragma unroll
      for (int t = 0; t < T_; ++t) {
        const float grt = GT[cb][t][sj];
        const float rin_t = rdlane(rinv, t);
        float y0 = 0.f, y1 = 0.f;
        #pragma unroll
        for (int j = 0; j < T_; ++j) if (j < t) {
          const float gjt = rdlane(grt, j);
          y0 = fmaf(gjt, cu0[j], y0);
          y1 = fmaf(gjt, cu1[j], y1);
        }
        const float2 rv  = *reinterpret_cast<const float2*>(&rawL[t][2*lane]);
        const float2 vvt = *reinterpret_cast<const float2*>(&vS[cb][t][2*lane]);
        const float pred0 = rin_t * (rv.x - y0);
        const float pred1 = rin_t * (rv.y - y1);
        const float s0 = pred0 - vvt.x, s1 = pred1 - vvt.y;
        const float s2 = wave_sum64(fmaf(s0, s0, s1 * s1));
        const float gg = 1.0f / (1.0f + __expf((THR_ - sqrtf(s2)) * ITEMP_));
        if (lane == 0) gateL[c*T_ + t] = gg;
        const float ct = gg * rin_t;
        const float u0 = fmaf(LRP1_, pred0, -(LR_ * vvt.x));
        const float u1 = fmaf(LRP1_, pred1, -(LR_ * vvt.y));
        cu0[t] = ct * u0; cu1[t] = ct * u1;
        *reinterpret_cast<float2*>(&cuL[t][2*lane]) = make_float2(cu0[t], cu1[t]);
      }
    } else {
      if (c + 1 < NC_) gramPhase(c + 1);
    }

    asm volatile("s_waitcnt lgkmcnt(0)" ::: "memory");
    __builtin_amdgcn_s_barrier();   // bar B: cuL + GT[c+1] visible; vS[cb] reads done
    asm volatile("" ::: "memory");

    // ---- update M -= sum_j cu_j (x) k_j  (zero LDS for k) ----
    #pragma unroll
    for (int j = 0; j < T_; ++j) {
      const float4 cA = *reinterpret_cast<const float4*>(&cuL[j][8*g]);
      const float4 cB = *reinterpret_cast<const float4*>(&cuL[j][8*g + 4]);
      const float cc8[8] = {cA.x, cA.y, cA.z, cA.w, cB.x, cB.y, cB.z, cB.w};
      #pragma unroll
      for (int rr = 0; rr < 8; ++rr) {
        mR[rr].x = fmaf(-cc8[rr], kR[j].x, mR[rr].x);
        mR[rr].y = fmaf(-cc8[rr], kR[j].y, mR[rr].y);
        mR[rr].z = fmaf(-cc8[rr], kR[j].z, mR[rr].z);
        mR[rr].w = fmaf(-cc8[rr], kR[j].w, mR[rr].w);
      }
    }

    if (c + 2 < NC_) stage(c + 2);     // safe: vS[cb]/kS[cb] readers retired at bar B
    if (c + 1 < NC_) refillK(c + 1);   // k regs for next chunk (kS[c+1] stable)
  }

  // ---- outputs ----
  {
    float4* Op = reinterpret_cast<float4*>(out + (size_t)b * DV_ * DK_);
    #pragma unroll
    for (int rr = 0; rr < 8; ++rr) Op[(8*g + rr) * 32 + h] = mR[rr];
    float2* Gp = reinterpret_cast<float2*>(out + (size_t)B_ * DV_ * DK_ + (size_t)b * S_);
    Gp[tid] = reinterpret_cast<const float2*>(gateL)[tid];
  }
}

extern "C" void kernel_launch(void* const* d_in, const int* in_sizes, int n_in,
                              void* d_out, int out_size, void* d_ws, size_t ws_size,
                              hipStream_t stream) {
  const float* mem = (const float*)d_in[0];
  const float* key = (const float*)d_in[1];
  const float* val = (const float*)d_in[2];
  float* out = (float*)d_out;
  sgm_kernel<<<B_, 512, 0, stream>>>(mem, key, val, out);
}

// Round 22
// 1520.869 us; speedup vs baseline: 1.6105x; 1.0067x over previous
//
#include <hip/hip_runtime.h>
#include <math.h>

#define B_    64
#define S_    1024
#define DK_   128
#define DV_   128
#define T_    16
#define NC_   (S_ / T_)
#define KP_   132          // padded LDS row stride
#define LR_   0.1f
#define LRP1_ 1.1f
#define THR_  0.1f
#define ITEMP_ 10.0f
#define EPS_  1e-6f

template<int CTRL>
__device__ __forceinline__ float dpp_add(float x) {
  int t = __builtin_amdgcn_update_dpp(0, __float_as_int(x), CTRL, 0xf, 0xf, true);
  return x + __int_as_float(t);
}
__device__ __forceinline__ float wave_sum64(float x) {
  x = dpp_add<0x111>(x); x = dpp_add<0x112>(x); x = dpp_add<0x114>(x);
  x = dpp_add<0x118>(x); x = dpp_add<0x142>(x); x = dpp_add<0x143>(x);
  return __int_as_float(__builtin_amdgcn_readlane(__float_as_int(x), 63));
}
// sum over 32 consecutive lanes, pure DPP; valid in lanes 31 and 63
__device__ __forceinline__ float half32_sum(float x) {
  x = dpp_add<0x111>(x); x = dpp_add<0x112>(x);
  x = dpp_add<0x114>(x); x = dpp_add<0x118>(x);
  x = dpp_add<0x142>(x);   // row_bcast:15 -> lane31 += lane15, lane63 += lane47
  return x;
}
__device__ __forceinline__ float rdlane(float v, int l) {
  return __int_as_float(__builtin_amdgcn_readlane(__float_as_int(v), l));
}
__device__ __forceinline__ float dot4(float4 a, float4 b) {
  return fmaf(a.x, b.x, fmaf(a.y, b.y, fmaf(a.z, b.z, a.w * b.w)));
}
__device__ __forceinline__ void gll16(const float* g, float* l) {
  __builtin_amdgcn_global_load_lds(
      (const __attribute__((address_space(1))) unsigned int*)g,
      (__attribute__((address_space(3))) unsigned int*)l, 16, 0, 0);
}
#define PIN4(v) asm volatile("" : "+v"(v.x), "+v"(v.y), "+v"(v.z), "+v"(v.w))

__global__ __launch_bounds__(512, 1)
void sgm_kernel(const float* __restrict__ mem_in,
                const float* __restrict__ key,
                const float* __restrict__ value,
                float* __restrict__ out) {
  const int b = blockIdx.x, tid = threadIdx.x;
  const int g = tid >> 5;      // rowgroup 0..15 -> rows 8g..8g+7
  const int h = tid & 31;      // col chunk: float4 idx h within a row
  const int lane = tid & 63, wv = tid >> 6;

  __shared__ __align__(16) float kS[2][T_][KP_];   // k copy: Gram + kR refill only
  __shared__ __align__(16) float vS[2][T_][KP_];   // v: serial (wave0) only
  __shared__ __align__(16) float rawL[T_][KP_];
  __shared__ __align__(16) float cuL[T_][DK_];
  __shared__ __align__(16) float GT[2][T_][T_];    // GT[p][t][j] = k_j.k_t (j<=t)
  __shared__ __align__(16) float gateL[S_];

  float4 mR[8];   // rows 8g..8g+7, cols 4h..4h+3
  {
    const float4* Mp = reinterpret_cast<const float4*>(mem_in + (size_t)b * DV_ * DK_);
    #pragma unroll
    for (int rr = 0; rr < 8; ++rr) mR[rr] = Mp[(8*g + rr) * 32 + h];
  }
  const float* kb = key   + (size_t)b * S_ * DK_;
  const float* vb = value + (size_t)b * S_ * DV_;

  float4 kR[T_];  // whole chunk's k for this thread's 4 cols (64 VGPR, pinned)

  auto stage = [&](int cc) {
    if (wv == 1 && lane < 32) {
      #pragma unroll
      for (int t = 0; t < T_; ++t)
        gll16(kb + (size_t)(cc*T_ + t)*DK_ + lane*4, &kS[cc & 1][t][0]);
    }
    if (wv == 2 && lane < 32) {
      #pragma unroll
      for (int t = 0; t < T_; ++t)
        gll16(vb + (size_t)(cc*T_ + t)*DV_ + lane*4, &vS[cc & 1][t][0]);
    }
  };
  auto refillK = [&](int cc) {   // LDS -> regs, pinned
    const int pb = cc & 1;
    #pragma unroll
    for (int t = 0; t < T_; ++t) {
      kR[t] = reinterpret_cast<const float4*>(&kS[pb][t][0])[h];
      PIN4(kR[t]);
    }
  };
  auto gramPhase = [&](int cc) {   // waves 1-7: 136 pairs (incl diag), 2-lane teams
    const int cb1 = cc & 1;
    const int p = (tid - 64) >> 1, h2 = tid & 1;
    if (wv > 0 && p < 136) {
      int t = 0, pp = p;
      while (pp > t) { pp -= (t + 1); ++t; }   // p = t(t+1)/2 + j, j<=t
      const int j = pp;
      const float4* kj4 = reinterpret_cast<const float4*>(&kS[cb1][j][h2*64]);
      const float4* kt4 = reinterpret_cast<const float4*>(&kS[cb1][t][h2*64]);
      float acc = 0.f;
      #pragma unroll
      for (int i = 0; i < 16; ++i) acc += dot4(kj4[i], kt4[i]);
      int sw = __builtin_amdgcn_update_dpp(0, __float_as_int(acc), 0xB1, 0xf, 0xf, true);
      const float tot = acc + __int_as_float(sw);
      if (h2 == 0) GT[cb1][t][j] = tot;
    }
  };

  // ---- prologue ----
  stage(0); stage(1);
  __syncthreads();               // drains vmcnt: kS/vS[0],[1] resident
  refillK(0);
  gramPhase(0);
  asm volatile("s_waitcnt lgkmcnt(0)" ::: "memory");
  __builtin_amdgcn_s_barrier();  // GT[0] visible
  asm volatile("" ::: "memory");

  for (int c = 0; c < NC_; ++c) {
    const int cb = c & 1;

    // ---- matvec raw_t = M . k_t  (zero LDS for k; pure-DPP reduce) ----
    #pragma unroll
    for (int t = 0; t < T_; ++t) {
      float a0 = dot4(mR[0], kR[t]), a1 = dot4(mR[1], kR[t]);
      float a2 = dot4(mR[2], kR[t]), a3 = dot4(mR[3], kR[t]);
      float a4 = dot4(mR[4], kR[t]), a5 = dot4(mR[5], kR[t]);
      float a6 = dot4(mR[6], kR[t]), a7 = dot4(mR[7], kR[t]);
      a0 = half32_sum(a0); a1 = half32_sum(a1); a2 = half32_sum(a2); a3 = half32_sum(a3);
      a4 = half32_sum(a4); a5 = half32_sum(a5); a6 = half32_sum(a6); a7 = half32_sum(a7);
      if (h == 31) {   // lanes 31,63: full 32-lane sums for rows 8g..8g+7
        *reinterpret_cast<float4*>(&rawL[t][8*g])     = make_float4(a0, a1, a2, a3);
        *reinterpret_cast<float4*>(&rawL[t][8*g + 4]) = make_float4(a4, a5, a6, a7);
      }
    }

    if (wv == 1 || wv == 2) asm volatile("s_waitcnt vmcnt(0)" ::: "memory");
    asm volatile("s_waitcnt lgkmcnt(0)" ::: "memory");
    __builtin_amdgcn_s_barrier();   // bar A: rawL ready; kS/vS[c+1] resident
    asm volatile("" ::: "memory");

    if (wv == 0) {
      // ---- serial phase (hidden under waves 1-7's Gram) ----
      const int sj = lane & 15;
      const float rinv = 1.0f / (sqrtf(GT[cb][sj][sj]) + EPS_);
      float cu0[T_], cu1[T_];
      #pragma unroll
      for (int t = 0; t < T_; ++t) {
        const float grt = GT[cb][t][sj];
        const float rin_t = rdlane(rinv, t);
        float y0 = 0.f, y1 = 0.f;
        #pragma unroll
        for (int j = 0; j < T_; ++j) if (j < t) {
          const float gjt = rdlane(grt, j);
          y0 = fmaf(gjt, cu0[j], y0);
          y1 = fmaf(gjt, cu1[j], y1);
        }
        const float2 rv  = *reinterpret_cast<const float2*>(&rawL[t][2*lane]);
        const float2 vvt = *reinterpret_cast<const float2*>(&vS[cb][t][2*lane]);
        const float pred0 = rin_t * (rv.x - y0);
        const float pred1 = rin_t * (rv.y - y1);
        const float s0 = pred0 - vvt.x, s1 = pred1 - vvt.y;
        const float s2 = wave_sum64(fmaf(s0, s0, s1 * s1));
        const float gg = 1.0f / (1.0f + __expf((THR_ - sqrtf(s2)) * ITEMP_));
        if (lane == 0) gateL[c*T_ + t] = gg;
        const float ct = gg * rin_t;
        const float u0 = fmaf(LRP1_, pred0, -(LR_ * vvt.x));
        const float u1 = fmaf(LRP1_, pred1, -(LR_ * vvt.y));
        cu0[t] = ct * u0; cu1[t] = ct * u1;
        *reinterpret_cast<float2*>(&cuL[t][2*lane]) = make_float2(cu0[t], cu1[t]);
      }
    } else {
      if (c + 1 < NC_) gramPhase(c + 1);
    }

    asm volatile("s_waitcnt lgkmcnt(0)" ::: "memory");
    __builtin_amdgcn_s_barrier();   // bar B: cuL + GT[c+1] visible; vS[cb] reads done
    asm volatile("" ::: "memory");

    // ---- update M -= sum_j cu_j (x) k_j  (zero LDS for k) ----
    #pragma unroll
    for (int j = 0; j < T_; ++j) {
      const float4 cA = *reinterpret_cast<const float4*>(&cuL[j][8*g]);
      const float4 cB = *reinterpret_cast<const float4*>(&cuL[j][8*g + 4]);
      const float cc8[8] = {cA.x, cA.y, cA.z, cA.w, cB.x, cB.y, cB.z, cB.w};
      #pragma unroll
      for (int rr = 0; rr < 8; ++rr) {
        mR[rr].x = fmaf(-cc8[rr], kR[j].x, mR[rr].x);
        mR[rr].y = fmaf(-cc8[rr], kR[j].y, mR[rr].y);
        mR[rr].z = fmaf(-cc8[rr], kR[j].z, mR[rr].z);
        mR[rr].w = fmaf(-cc8[rr], kR[j].w, mR[rr].w);
      }
    }

    if (c + 2 < NC_) stage(c + 2);     // safe: vS[cb]/kS[cb] readers retired at bar B
    if (c + 1 < NC_) refillK(c + 1);   // k regs for next chunk (kS[c+1] stable)
  }

  // ---- outputs ----
  {
    float4* Op = reinterpret_cast<float4*>(out + (size_t)b * DV_ * DK_);
    #pragma unroll
    for (int rr = 0; rr < 8; ++rr) Op[(8*g + rr) * 32 + h] = mR[rr];
    float2* Gp = reinterpret_cast<float2*>(out + (size_t)B_ * DV_ * DK_ + (size_t)b * S_);
    Gp[tid] = reinterpret_cast<const float2*>(gateL)[tid];
  }
}

extern "C" void kernel_launch(void* const* d_in, const int* in_sizes, int n_in,
                              void* d_out, int out_size, void* d_ws, size_t ws_size,
                              hipStream_t stream) {
  const float* mem = (const float*)d_in[0];
  const float* key = (const float*)d_in[1];
  const float* val = (const float*)d_in[2];
  float* out = (float*)d_out;
  sgm_kernel<<<B_, 512, 0, stream>>>(mem, key, val, out);
}

// Round 23
// 554.878 us; speedup vs baseline: 4.4143x; 2.7409x over previous
//
#include <hip/hip_runtime.h>
#include <math.h>

#define B_    64
#define S_    1024
#define DK_   128
#define DV_   128
#define T_    16
#define NC_   (S_ / T_)
#define KP_   (DK_ + 4)    // padded LDS row stride
#define LR_   0.1f
#define LRP1_ 1.1f
#define THR_  0.1f
#define ITEMP_ 10.0f
#define EPS_  1e-6f

template<int CTRL>
__device__ __forceinline__ float dpp_add(float x) {
  int t = __builtin_amdgcn_update_dpp(0, __float_as_int(x), CTRL, 0xf, 0xf, true);
  return x + __int_as_float(t);
}
__device__ __forceinline__ float wave_sum64(float x) {
  x = dpp_add<0x111>(x); x = dpp_add<0x112>(x); x = dpp_add<0x114>(x);
  x = dpp_add<0x118>(x); x = dpp_add<0x142>(x); x = dpp_add<0x143>(x);
  return __int_as_float(__builtin_amdgcn_readlane(__float_as_int(x), 63));
}
__device__ __forceinline__ float row16_sum(float x) {  // valid in lane 15 of each 16-group
  x = dpp_add<0x111>(x); x = dpp_add<0x112>(x);
  x = dpp_add<0x114>(x); x = dpp_add<0x118>(x);
  return x;
}
__device__ __forceinline__ float rdlane(float v, int l) {
  return __int_as_float(__builtin_amdgcn_readlane(__float_as_int(v), l));
}
__device__ __forceinline__ float dot4(float4 a, float4 b) {
  return fmaf(a.x, b.x, fmaf(a.y, b.y, fmaf(a.z, b.z, a.w * b.w)));
}
__device__ __forceinline__ void gll16(const float* g, float* l) {
  __builtin_amdgcn_global_load_lds(
      (const __attribute__((address_space(1))) unsigned int*)g,
      (__attribute__((address_space(3))) unsigned int*)l, 16, 0, 0);
}

__global__ __launch_bounds__(512, 2)
void sgm_kernel(const float* __restrict__ mem_in,
                const float* __restrict__ key,
                const float* __restrict__ value,
                float* __restrict__ out) {
  const int b = blockIdx.x, tid = threadIdx.x;
  const int g = tid >> 4, h = tid & 15, lane = tid & 63, wv = tid >> 6;

  __shared__ __align__(16) float kS[2][T_][KP_];   // k copy: Gram + refill + ky reads
  __shared__ __align__(16) float vS[2][T_][KP_];   // v: serial (wave0) only
  __shared__ __align__(16) float rawL[T_][DK_];
  __shared__ __align__(16) float cuL[T_][DK_];
  __shared__ __align__(16) float GT[2][T_][T_];    // GT[p][t][j] = k_j.k_t (j<=t)
  __shared__ __align__(16) float gateL[S_];

  float4 mA[4], mB[4];
  {
    const float4* Mp = reinterpret_cast<const float4*>(mem_in + (size_t)b * DV_ * DK_);
    #pragma unroll
    for (int rr = 0; rr < 4; ++rr) {
      mA[rr] = Mp[(4*g + rr) * 32 + h];
      mB[rr] = Mp[(4*g + rr) * 32 + 16 + h];
    }
  }
  const float* kb = key   + (size_t)b * S_ * DK_;
  const float* vb = value + (size_t)b * S_ * DV_;

  auto stage = [&](int cc) {
    if (wv == 0 && lane < 32) {
      #pragma unroll
      for (int t = 0; t < T_; ++t)
        gll16(kb + (size_t)(cc*T_ + t)*DK_ + lane*4, &kS[cc & 1][t][0]);
    }
    if (wv == 1 && lane < 32) {
      #pragma unroll
      for (int t = 0; t < T_; ++t)
        gll16(vb + (size_t)(cc*T_ + t)*DV_ + lane*4, &vS[cc & 1][t][0]);
    }
  };

  float4 kxR[16];   // current chunk's k, first-half float4 (col idx h) per t

  // M -= sum_j cu_j (x) k_j ; first half from kxR regs, second half from LDS
  auto applyUpdate = [&](int pb) {
    #pragma unroll
    for (int j = 0; j < T_; ++j) {
      const float4* kj = reinterpret_cast<const float4*>(&kS[pb][j][0]);
      const float4 ky = kj[16 + h];
      const float4 cu = *reinterpret_cast<const float4*>(&cuL[j][4 * g]);
      const float cc[4] = {cu.x, cu.y, cu.z, cu.w};
      #pragma unroll
      for (int rr = 0; rr < 4; ++rr) {
        mA[rr].x = fmaf(-cc[rr], kxR[j].x, mA[rr].x);
        mA[rr].y = fmaf(-cc[rr], kxR[j].y, mA[rr].y);
        mA[rr].z = fmaf(-cc[rr], kxR[j].z, mA[rr].z);
        mA[rr].w = fmaf(-cc[rr], kxR[j].w, mA[rr].w);
        mB[rr].x = fmaf(-cc[rr], ky.x, mB[rr].x);
        mB[rr].y = fmaf(-cc[rr], ky.y, mB[rr].y);
        mB[rr].z = fmaf(-cc[rr], ky.z, mB[rr].z);
        mB[rr].w = fmaf(-cc[rr], ky.w, mB[rr].w);
      }
    }
  };

  // waves 1-7: 136 pairs (incl diag, j<=t), 2-lane teams, chunk cc
  auto gramPhase = [&](int cc) {
    const int cb1 = cc & 1;
    const int p = (tid - 64) >> 1, h2 = tid & 1;
    if (wv > 0 && p < 136) {
      int t = 0, pp = p;
      while (pp > t) { pp -= (t + 1); ++t; }   // p = t(t+1)/2 + j, j<=t
      const int j = pp;
      const float4* kj4 = reinterpret_cast<const float4*>(&kS[cb1][j][h2*64]);
      const float4* kt4 = reinterpret_cast<const float4*>(&kS[cb1][t][h2*64]);
      float acc = 0.f;
      #pragma unroll
      for (int i = 0; i < 16; ++i) acc += dot4(kj4[i], kt4[i]);
      int sw = __builtin_amdgcn_update_dpp(0, __float_as_int(acc), 0xB1, 0xf, 0xf, true);
      const float tot = acc + __int_as_float(sw);
      if (h2 == 0) GT[cb1][t][j] = tot;
    }
  };

  // ---- prologue: stage chunk 0, Gram(0) ----
  stage(0);
  if (wv < 2) asm volatile("s_waitcnt vmcnt(0)" ::: "memory");
  __syncthreads();
  gramPhase(0);
  asm volatile("s_waitcnt lgkmcnt(0)" ::: "memory");
  __builtin_amdgcn_s_barrier();          // GT[0] visible
  asm volatile("" ::: "memory");

  for (int c = 0; c < NC_; ++c) {
    const int cb = c & 1;

    // ---- apply previous chunk's rank-16 update ----
    if (c > 0) applyUpdate((c - 1) & 1);

    // ---- load new chunk's k first-halves into registers ----
    #pragma unroll
    for (int t = 0; t < T_; ++t)
      kxR[t] = reinterpret_cast<const float4*>(&kS[cb][t][0])[h];

    asm volatile("s_waitcnt lgkmcnt(0)" ::: "memory");
    __builtin_amdgcn_s_barrier();        // bar1: old-parity readers retired
    asm volatile("" ::: "memory");
    if (c + 1 < NC_) stage(c + 1);       // safe: parity (c+1)&1 readers done

    // ---- matvec raw_t = M . k_t ----
    #pragma unroll
    for (int t = 0; t < T_; ++t) {
      const float4 ky = reinterpret_cast<const float4*>(&kS[cb][t][0])[16 + h];
      float a0 = dot4(mA[0], kxR[t]) + dot4(mB[0], ky);
      float a1 = dot4(mA[1], kxR[t]) + dot4(mB[1], ky);
      float a2 = dot4(mA[2], kxR[t]) + dot4(mB[2], ky);
      float a3 = dot4(mA[3], kxR[t]) + dot4(mB[3], ky);
      a0 = row16_sum(a0); a1 = row16_sum(a1);
      a2 = row16_sum(a2); a3 = row16_sum(a3);
      if (h == 15)
        *reinterpret_cast<float4*>(&rawL[t][4 * g]) = make_float4(a0, a1, a2, a3);
    }

    // stager waves: kS/vS[c+1] must be resident for Gram(c+1) / serial(c+1)
    if (wv < 2) asm volatile("s_waitcnt vmcnt(0)" ::: "memory");
    asm volatile("s_waitcnt lgkmcnt(0)" ::: "memory");
    __builtin_amdgcn_s_barrier();        // bar2: rawL + kS/vS[c+1] ready
    asm volatile("" ::: "memory");

    if (wv == 0) {
      // ---- serial phase (hidden under waves 1-7's Gram(c+1)) ----
      const int sj = lane & 15;
      const float rinv = 1.0f / (sqrtf(GT[cb][sj][sj]) + EPS_);
      float cu0[T_], cu1[T_];
      #pragma unroll
      for (int t = 0; t < T_; ++t) {
        const float grt = GT[cb][t][sj];
        const float rin_t = rdlane(rinv, t);
        float y0 = 0.f, y1 = 0.f;
        #pragma unroll
        for (int j = 0; j < T_; ++j) if (j < t) {
          const float gjt = rdlane(grt, j);
          y0 = fmaf(gjt, cu0[j], y0);
          y1 = fmaf(gjt, cu1[j], y1);
        }
        const float2 rv  = *reinterpret_cast<const float2*>(&rawL[t][2*lane]);
        const float2 vvt = *reinterpret_cast<const float2*>(&vS[cb][t][2*lane]);
        const float pred0 = rin_t * (rv.x - y0);
        const float pred1 = rin_t * (rv.y - y1);
        const float s0 = pred0 - vvt.x, s1 = pred1 - vvt.y;
        const float s2 = wave_sum64(fmaf(s0, s0, s1 * s1));
        const float gg = 1.0f / (1.0f + __expf((THR_ - sqrtf(s2)) * ITEMP_));
        if (lane == 0) gateL[c*T_ + t] = gg;
        const float ct = gg * rin_t;
        const float u0 = fmaf(LRP1_, pred0, -(LR_ * vvt.x));
        const float u1 = fmaf(LRP1_, pred1, -(LR_ * vvt.y));
        cu0[t] = ct * u0; cu1[t] = ct * u1;
        *reinterpret_cast<float2*>(&cuL[t][2*lane]) = make_float2(cu0[t], cu1[t]);
      }
    } else {
      if (c + 1 < NC_) gramPhase(c + 1);  // GT[(c+1)&1], reads kS[(c+1)&1]
    }

    asm volatile("s_waitcnt lgkmcnt(0)" ::: "memory");
    __builtin_amdgcn_s_barrier();        // bar3: cuL + GT[c+1] visible
    asm volatile("" ::: "memory");
  }

  applyUpdate((NC_ - 1) & 1);

  // ---- outputs ----
  {
    float4* Op = reinterpret_cast<float4*>(out + (size_t)b * DV_ * DK_);
    #pragma unroll
    for (int rr = 0; rr < 4; ++rr) {
      Op[(4*g + rr) * 32 + h] = mA[rr];
      Op[(4*g + rr) * 32 + 16 + h] = mB[rr];
    }
    float2* Gp = reinterpret_cast<float2*>(out + (size_t)B_ * DV_ * DK_ + (size_t)b * S_);
    Gp[tid] = reinterpret_cast<const float2*>(gateL)[tid];
  }
}

extern "C" void kernel_launch(void* const* d_in, const int* in_sizes, int n_in,
                              void* d_out, int out_size, void* d_ws, size_t ws_size,
                              hipStream_t stream) {
  const float* mem = (const float*)d_in[0];
  const float* key = (const float*)d_in[1];
  const float* val = (const float*)d_in[2];
  float* out = (float*)d_out;
  sgm_kernel<<<B_, 512, 0, stream>>>(mem, key, val, out);
}